// Round 14
// baseline (157.315 us; speedup 1.0000x reference)
//
#include <hip/hip_runtime.h>

// OptPosEncBatch: per-point multi-feature 1D-linear codebook interpolation.
// coords [B=8, P=65536, F=3] f32, idx [B] i32, shape_code [C=64, S*F*CN=3072] f32
// out [B, P, C=64] f32.
//
// R11 post-mortem: R8 issue-ahead pipeline -> kernel ~48us (dur 151.2, best).
// Remaining gap vs ~23us overlap floor: TLP. Grid was 512 blocks = 2/CU and
// launch_bounds(512,4) capped residency at 16 waves/CU. R12: 1024 blocks
// (512 pts each) + launch_bounds(512,6) -> 3 resident blocks = 24 waves/CU,
// VGPR cap 85 (steady live set ~75-80). Pipeline structure unchanged.

#define CODE_NUM 64
#define NFEAT 3
#define NCHAN 64
#define NB 8
#define NP 65536
#define SLICE (CODE_NUM * NFEAT)      // 192 rows in the per-batch slice
#define ROW_STRIDE 3072               // SHAPE_NUM * NFEAT * CODE_NUM
#define NTHREADS 512
#define BLOCKS_PER_BATCH 128
#define PTS_PER_BLOCK (NP / BLOCKS_PER_BATCH)   // 512
#define PTS_PER_ITER (NTHREADS / 16)            // 32
#define NIT (PTS_PER_BLOCK / PTS_PER_ITER)      // 16

__global__ __launch_bounds__(NTHREADS, 6)   // 85-VGPR cap, 3 blocks/CU = 24 waves
void posenc_kernel(const float* __restrict__ coords,
                   const int* __restrict__ idx,
                   const float* __restrict__ shape_code,
                   float* __restrict__ out) {
    __shared__ float code_lds[SLICE * NCHAN];   // [row][chan], 48 KB

    const int bx    = blockIdx.x;
    const int b     = bx >> 7;                  // batch (128 blocks/batch)
    const int chunk = (bx & (BLOCKS_PER_BATCH - 1)) * PTS_PER_BLOCK;
    const int tid   = threadIdx.x;
    const size_t bp0 = (size_t)b * NP;

    // --- stage shape_code[c][base .. base+191] -> code_lds[j][c] ---
    const int base = idx[b] * SLICE;
    {
        const int c      = tid & 63;
        const int jchunk = tid >> 6;
        const float* src = shape_code + (size_t)c * ROW_STRIDE + base;
        #pragma unroll
        for (int jv = jchunk; jv < SLICE / 4; jv += NTHREADS / 64) {
            const float4 v = *reinterpret_cast<const float4*>(src + jv * 4);
            code_lds[(jv * 4 + 0) * NCHAN + c] = v.x;
            code_lds[(jv * 4 + 1) * NCHAN + c] = v.y;
            code_lds[(jv * 4 + 2) * NCHAN + c] = v.z;
            code_lds[(jv * 4 + 3) * NCHAN + c] = v.w;
        }
    }
    __syncthreads();

    const int gl   = tid & 15;
    const int pofs = tid >> 4;                  // 0..31
    const float* cp = coords + (bp0 + chunk) * NFEAT;
    float*       og = out + (bp0 + chunk) * NCHAN + gl * 4;

    const int inv0 = 0 * CODE_NUM * NCHAN + gl * 4;
    const int inv1 = 1 * CODE_NUM * NCHAN + gl * 4;
    const int inv2 = 2 * CODE_NUM * NCHAN + gl * 4;

// load coords for iteration IT into three named regs (vmcnt queue)
#define LOADC(IT, X0, X1, X2)                                                  \
    {                                                                          \
        const int _lp = (IT) * PTS_PER_ITER + pofs;                            \
        X0 = cp[_lp * 3 + 0];                                                  \
        X1 = cp[_lp * 3 + 1];                                                  \
        X2 = cp[_lp * 3 + 2];                                                  \
    }

// index math + issue 6 ds_read_b128 into the named frag (lgkm queue)
#define ISSUE(X0, X1, X2, F0, F1, F2, F3, F4, F5, W0, W1, W2)                  \
    {                                                                          \
        const float g0 = fmaf(X0, 31.5f, 31.5f);                               \
        const float g1 = fmaf(X1, 31.5f, 31.5f);                               \
        const float g2 = fmaf(X2, 31.5f, 31.5f);                               \
        int i0 = (int)floorf(g0); i0 = max(0, min(i0, CODE_NUM - 2));          \
        int i1 = (int)floorf(g1); i1 = max(0, min(i1, CODE_NUM - 2));          \
        int i2 = (int)floorf(g2); i2 = max(0, min(i2, CODE_NUM - 2));          \
        W0 = g0 - (float)i0;                                                   \
        W1 = g1 - (float)i1;                                                   \
        W2 = g2 - (float)i2;                                                   \
        const float* r0 = &code_lds[inv0 + i0 * NCHAN];                        \
        const float* r1 = &code_lds[inv1 + i1 * NCHAN];                        \
        const float* r2 = &code_lds[inv2 + i2 * NCHAN];                        \
        F0 = *reinterpret_cast<const float4*>(r0);                             \
        F1 = *reinterpret_cast<const float4*>(r0 + NCHAN);                     \
        F2 = *reinterpret_cast<const float4*>(r1);                             \
        F3 = *reinterpret_cast<const float4*>(r1 + NCHAN);                     \
        F4 = *reinterpret_cast<const float4*>(r2);                             \
        F5 = *reinterpret_cast<const float4*>(r2 + NCHAN);                     \
    }

// weighted reduce + 1KB coalesced store
#define CONSUME(IT, F0, F1, F2, F3, F4, F5, W0, W1, W2)                        \
    {                                                                          \
        const float u0 = 1.0f - W0, u1 = 1.0f - W1, u2 = 1.0f - W2;            \
        float4 acc;                                                            \
        acc.x = fmaf(u0, F0.x, W0 * F1.x);                                     \
        acc.y = fmaf(u0, F0.y, W0 * F1.y);                                     \
        acc.z = fmaf(u0, F0.z, W0 * F1.z);                                     \
        acc.w = fmaf(u0, F0.w, W0 * F1.w);                                     \
        acc.x = fmaf(u1, F2.x, fmaf(W1, F3.x, acc.x));                         \
        acc.y = fmaf(u1, F2.y, fmaf(W1, F3.y, acc.y));                         \
        acc.z = fmaf(u1, F2.z, fmaf(W1, F3.z, acc.z));                         \
        acc.w = fmaf(u1, F2.w, fmaf(W1, F3.w, acc.w));                         \
        acc.x = fmaf(u2, F4.x, fmaf(W2, F5.x, acc.x));                         \
        acc.y = fmaf(u2, F4.y, fmaf(W2, F5.y, acc.y));                         \
        acc.z = fmaf(u2, F4.z, fmaf(W2, F5.z, acc.z));                         \
        acc.w = fmaf(u2, F4.w, fmaf(W2, F5.w, acc.w));                         \
        *reinterpret_cast<float4*>(og + (size_t)((IT) * PTS_PER_ITER + pofs) * NCHAN) = acc; \
    }

    float4 A0, A1, A2, A3, A4, A5, B0, B1, B2, B3, B4, B5;
    float  wa0, wa1, wa2, wb0, wb1, wb2;
    float  cA0, cA1, cA2, cB0, cB1, cB2;

    // prologue: coords(0), coords(1); issue frag(0)
    LOADC(0, cA0, cA1, cA2);
    LOADC(1, cB0, cB1, cB2);
    ISSUE(cA0, cA1, cA2, A0, A1, A2, A3, A4, A5, wa0, wa1, wa2);

    // steady state per pair (it, it+1):
    //   coords(it+2) -> cA; issue frag(it+1) from cB; consume frag(it);
    //   coords(it+3) -> cB; issue frag(it+2) from cA; consume frag(it+1).
    #pragma unroll 1
    for (int it = 0; it <= NIT - 4; it += 2) {
        LOADC(it + 2, cA0, cA1, cA2);
        ISSUE(cB0, cB1, cB2, B0, B1, B2, B3, B4, B5, wb0, wb1, wb2);
        CONSUME(it, A0, A1, A2, A3, A4, A5, wa0, wa1, wa2);
        LOADC(it + 3, cB0, cB1, cB2);
        ISSUE(cA0, cA1, cA2, A0, A1, A2, A3, A4, A5, wa0, wa1, wa2);
        CONSUME(it + 1, B0, B1, B2, B3, B4, B5, wb0, wb1, wb2);
    }

    // epilogue: A holds frag(NIT-2), cB holds coords(NIT-1)
    ISSUE(cB0, cB1, cB2, B0, B1, B2, B3, B4, B5, wb0, wb1, wb2);
    CONSUME(NIT - 2, A0, A1, A2, A3, A4, A5, wa0, wa1, wa2);
    CONSUME(NIT - 1, B0, B1, B2, B3, B4, B5, wb0, wb1, wb2);

#undef LOADC
#undef ISSUE
#undef CONSUME
}

extern "C" void kernel_launch(void* const* d_in, const int* in_sizes, int n_in,
                              void* d_out, int out_size, void* d_ws, size_t ws_size,
                              hipStream_t stream) {
    const float* coords     = (const float*)d_in[0];
    const int*   idx        = (const int*)d_in[1];
    const float* shape_code = (const float*)d_in[2];
    float*       out        = (float*)d_out;

    dim3 grid(NB * BLOCKS_PER_BATCH);   // 1024 blocks
    dim3 block(NTHREADS);               // 512 threads
    posenc_kernel<<<grid, block, 0, stream>>>(coords, idx, shape_code, out);
}